// Round 4
// baseline (415.116 us; speedup 1.0000x reference)
//
#include <hip/hip_runtime.h>
#include <hip/hip_bf16.h>

// QuantizedLinear: out[64,8192] = x[64,8192] @ (alpha * ternary(W))^T + bias
// W is [O=8192, I=8192] fp32 row-major. Ternary {-1,0,+1} exact in bf16; alpha
// applied fp32 in epilogue; only x is rounded to bf16.
//
// Round-4 change (single-variable vs round 3): the 4.2M 8-way-conflicting
// device-scope atomicAdds (k-split epilogue) are replaced by plain stores
// into a fp32 partial buffer part[KSPLIT][64][8192] (16.8 MB of workspace),
// reduced by a tiny bandwidth-bound kernel that also fuses bias. Staging /
// compute loop is identical to round 3 (async global_load_lds width-16,
// double-buffered LDS, XOR-swizzled both-sides).

typedef __attribute__((ext_vector_type(8))) short short8;   // 8 bf16 = 4 VGPRs
typedef __attribute__((ext_vector_type(4))) float floatx4;  // MFMA acc

#define B_DIM 64
#define K_DIM 8192
#define O_DIM 8192
#define BN 64                      // W rows (output cols) per block
#define BK 64                      // k per tile
#define KSPLIT 8
#define KCHUNK (K_DIM / KSPLIT)    // 1024 k per block
#define NT (KCHUNK / BK)           // 16 tiles
#define PART_STRIDE ((size_t)B_DIM * O_DIM)   // floats per k-slice partial

__device__ __forceinline__ void gload_lds16(const void* g, void* l) {
  __builtin_amdgcn_global_load_lds(
      (const __attribute__((address_space(1))) void*)g,
      (__attribute__((address_space(3))) void*)l, 16, 0, 0);
}

// ---- prep: x fp32 -> bf16 workspace (vectorized), nothing else ----
__global__ __launch_bounds__(256) void prep_kernel(
    const float* __restrict__ x, __hip_bfloat16* __restrict__ xbf) {
  int idx = (blockIdx.x * 256 + threadIdx.x) * 8;
  float4 v0 = *(const float4*)(x + idx);
  float4 v1 = *(const float4*)(x + idx + 4);
  __hip_bfloat16 h[8];
  h[0] = __float2bfloat16(v0.x); h[1] = __float2bfloat16(v0.y);
  h[2] = __float2bfloat16(v0.z); h[3] = __float2bfloat16(v0.w);
  h[4] = __float2bfloat16(v1.x); h[5] = __float2bfloat16(v1.y);
  h[6] = __float2bfloat16(v1.z); h[7] = __float2bfloat16(v1.w);
  *(short8*)&xbf[idx] = *(const short8*)h;
}

// ---- main GEMM: 1024 blocks (128 n-tiles x 8 k-slices), 256 threads ----
__global__ __launch_bounds__(256, 3) void gemm_kernel(
    const float* __restrict__ w, const unsigned short* __restrict__ xbf,
    const float* __restrict__ alpha, float* __restrict__ part) {
  __shared__ __align__(16) float Ws[2][BN][BK];             // 32 KB
  __shared__ __align__(16) unsigned short Xs[2][B_DIM][BK]; // 16 KB

  const int tid = threadIdx.x;
  const int nt = blockIdx.x & 127;   // n-tile (fast dim)
  const int ks = blockIdx.x >> 7;    // k-slice 0..7
  const int n0 = nt * BN;
  const int k0 = ks * KCHUNK;

  const int wv  = tid >> 6;    // wave 0..3
  const int ln  = tid & 63;
  const int lhi = ln >> 4;     // 0..3 -> k-subgroup of 8
  const int llo = ln & 15;     // fragment row

  // Compute-side lane identity: W row (output col) = wv*16 + llo.
  const int nrow = n0 + wv * 16 + llo;
  const float av  = alpha[nrow];
  const float thr = 0.5f * (av + 1e-8f);   // |w| > 0.5*(alpha+eps) -> +/-1
  const int sw = (llo & 7) << 4;           // read-side XOR swizzle (bytes)

  floatx4 acc[4];
#pragma unroll
  for (int i = 0; i < 4; ++i) acc[i] = (floatx4){0.f, 0.f, 0.f, 0.f};

  auto tern = [&](float v) -> short {
    return v > thr ? (short)0x3F80
                   : (v < -thr ? (short)(unsigned short)0xBF80 : (short)0);
  };

  // ---- async staging: every instruction is a contiguous 1 KB wave segment ----
  auto stage = [&](int buf, int kt) {
    const size_t kb = (size_t)(k0 + kt * BK);
    // W: 4 instrs/wave, 4 rows x 256 B each; source pre-swizzled within row.
#pragma unroll
    for (int j = 0; j < 4; ++j) {
      const int r0  = wv * 16 + j * 4;
      const int row = r0 + (ln >> 4);
      const char* src = (const char*)w
          + ((size_t)(n0 + row) * K_DIM + kb) * 4
          + (((ln & 15) * 16) ^ ((row & 7) << 4));
      gload_lds16(src, &Ws[buf][r0][0]);
    }
    // X: 2 instrs/wave, 8 rows x 128 B each; source pre-swizzled within row.
#pragma unroll
    for (int j = 0; j < 2; ++j) {
      const int r0  = wv * 16 + j * 8;
      const int row = r0 + (ln >> 3);
      const char* src = (const char*)xbf
          + ((size_t)row * K_DIM + kb) * 2
          + (((ln & 7) * 16) ^ ((row & 7) << 4));
      gload_lds16(src, &Xs[buf][r0][0]);
    }
  };

  auto compute = [&](int buf) {
    const char* wrow = (const char*)&Ws[buf][wv * 16 + llo][0];
#pragma unroll
    for (int kk = 0; kk < 2; ++kk) {
      const int cW = kk * 128 + lhi * 32;
      float4 f0 = *(const float4*)(wrow + ((cW)      ^ sw));
      float4 f1 = *(const float4*)(wrow + ((cW + 16) ^ sw));
      short8 b;
      b[0] = tern(f0.x); b[1] = tern(f0.y); b[2] = tern(f0.z); b[3] = tern(f0.w);
      b[4] = tern(f1.x); b[5] = tern(f1.y); b[6] = tern(f1.z); b[7] = tern(f1.w);
      const int cX = kk * 64 + lhi * 16;
#pragma unroll
      for (int mt = 0; mt < 4; ++mt) {
        short8 a = *(const short8*)((const char*)&Xs[buf][mt * 16 + llo][0]
                                    + (cX ^ sw));
        acc[mt] = __builtin_amdgcn_mfma_f32_16x16x32_bf16(a, b, acc[mt], 0, 0, 0);
      }
    }
  };

  stage(0, 0);
  __syncthreads();                 // drains vmcnt -> tile 0 resident
  int buf = 0;
  for (int kt = 0; kt < NT; ++kt) {
    if (kt + 1 < NT) stage(buf ^ 1, kt + 1);  // async, overlaps compute
    compute(buf);
    __syncthreads();               // all reads of buf done + buf^1 landed
    buf ^= 1;
  }

  // epilogue: C/D layout col=lane&15 (n), row=(lane>>4)*4+reg (m).
  // Plain stores into this k-slice's private partial plane -- NO atomics.
  float* pout = part + (size_t)ks * PART_STRIDE;
#pragma unroll
  for (int mt = 0; mt < 4; ++mt) {
    const int m = mt * 16 + lhi * 4;
#pragma unroll
    for (int r = 0; r < 4; ++r) {
      pout[(size_t)(m + r) * O_DIM + nrow] = acc[mt][r] * av;
    }
  }
}

// ---- reduce: out = bias + sum_ks part[ks]; fully coalesced float4 ----
__global__ __launch_bounds__(256) void reduce_kernel(
    const float* __restrict__ part, const float* __restrict__ bias,
    float* __restrict__ out) {
  const size_t base = (size_t)(blockIdx.x * 256 + threadIdx.x) * 4;
  float4 s = *(const float4*)(bias + (base & (size_t)(O_DIM - 1)));
#pragma unroll
  for (int ks = 0; ks < KSPLIT; ++ks) {
    float4 p = *(const float4*)(part + ks * PART_STRIDE + base);
    s.x += p.x; s.y += p.y; s.z += p.z; s.w += p.w;
  }
  *(float4*)(out + base) = s;
}

extern "C" void kernel_launch(void* const* d_in, const int* in_sizes, int n_in,
                              void* d_out, int out_size, void* d_ws, size_t ws_size,
                              hipStream_t stream) {
  const float* x     = (const float*)d_in[0];  // [64, 8192]
  const float* w     = (const float*)d_in[1];  // [8192, 8192]
  const float* alpha = (const float*)d_in[2];  // [8192, 1]
  const float* bias  = (const float*)d_in[3];  // [8192]
  float* out = (float*)d_out;                  // [64, 8192]

  // workspace layout: [0, 16.8MB) partials, [32MB, 33MB) xbf
  float* part = (float*)d_ws;
  __hip_bfloat16* xbf = (__hip_bfloat16*)((char*)d_ws + (32u << 20));

  prep_kernel<<<(B_DIM * K_DIM) / (256 * 8), 256, 0, stream>>>(x, xbf);
  gemm_kernel<<<(O_DIM / BN) * KSPLIT, 256, 0, stream>>>(
      w, (const unsigned short*)xbf, alpha, part);
  reduce_kernel<<<(B_DIM * O_DIM) / (256 * 4), 256, 0, stream>>>(part, bias, out);
}